// Round 1
// baseline (163.314 us; speedup 1.0000x reference)
//
#include <hip/hip_runtime.h>
#include <hip/hip_bf16.h>

// CrossViewContrast: loss = -mean_i( 2*<z1n_i,z2n_i> - log(sum_j exp(2*<z1n_i,z2n_j>) + 1e-8) )
// N=16384, D=128. Strategy: bf16 MFMA GEMM (never materialize sim), fp32 diagonal.

#define N_ROWS 16384
#define DIM 128
#define JSPLIT 8
#define COLS_PER_BLOCK (N_ROWS / JSPLIT)   // 2048
#define JCHUNK 128
#define NCHUNK (COLS_PER_BLOCK / JCHUNK)   // 16
#define ROWS_PER_BLOCK 256
#define ITILES (N_ROWS / ROWS_PER_BLOCK)   // 64

typedef __attribute__((ext_vector_type(8))) short short8;   // 8 bf16 = 4 VGPRs (MFMA A/B frag)
typedef __attribute__((ext_vector_type(4))) float floatx4;  // MFMA C/D frag

__device__ inline void gload_lds16(const void* gptr, void* lptr) {
  __builtin_amdgcn_global_load_lds(
      (const __attribute__((address_space(1))) void*)gptr,
      (__attribute__((address_space(3))) void*)lptr, 16, 0, 0);
}

// ---------------- Kernel 1: row norms + diagonal + bf16 cast + denom zero ----
__global__ __launch_bounds__(256) void norm_kernel(
    const float* __restrict__ z1, const float* __restrict__ z2,
    __hip_bfloat16* __restrict__ z1n, __hip_bfloat16* __restrict__ z2n,
    float* __restrict__ diag, float* __restrict__ denom) {
  int tid = threadIdx.x;
  int wave = tid >> 6, lane = tid & 63;
  int row = blockIdx.x * 4 + wave;   // one wave per row
  const float2* p1 = (const float2*)(z1 + (size_t)row * DIM);
  const float2* p2 = (const float2*)(z2 + (size_t)row * DIM);
  float2 a = p1[lane], b = p2[lane];
  float s11 = a.x * a.x + a.y * a.y;
  float s22 = b.x * b.x + b.y * b.y;
  float s12 = a.x * b.x + a.y * b.y;
#pragma unroll
  for (int m = 32; m >= 1; m >>= 1) {
    s11 += __shfl_xor(s11, m);
    s22 += __shfl_xor(s22, m);
    s12 += __shfl_xor(s12, m);
  }
  float inv1 = 1.0f / fmaxf(sqrtf(s11), 1e-12f);  // torch F.normalize eps
  float inv2 = 1.0f / fmaxf(sqrtf(s22), 1e-12f);
  __hip_bfloat162 o1, o2;
  o1.x = __float2bfloat16(a.x * inv1); o1.y = __float2bfloat16(a.y * inv1);
  o2.x = __float2bfloat16(b.x * inv2); o2.y = __float2bfloat16(b.y * inv2);
  ((__hip_bfloat162*)(z1n + (size_t)row * DIM))[lane] = o1;
  ((__hip_bfloat162*)(z2n + (size_t)row * DIM))[lane] = o2;
  if (lane == 0) diag[row] = s12 * inv1 * inv2;          // exact fp32 diagonal
  if (wave == 0 && lane < 4) denom[blockIdx.x * 4 + lane] = 0.0f;
}

// ---------------- Kernel 2: denom_i += sum_j exp(2*sim_ij), bf16 MFMA -------
// Block: 4 waves; wave w owns rows [i0+w*64, +64) (A frags in registers).
// B chunk: 128 cols x 128 K bf16 = 32 KB staged in LDS via global_load_lds,
// with 16B-granule XOR swizzle (phys = logical ^ (row&15)) to kill the 16-way
// ds_read_b128 bank conflict of the row-major layout.
__global__ __launch_bounds__(256) void sim_kernel(
    const __hip_bfloat16* __restrict__ z1n,
    const __hip_bfloat16* __restrict__ z2n,
    float* __restrict__ denom) {
  __shared__ short8 lds8[JCHUNK * 16];  // 2048 granules * 16 B = 32 KB

  int tid = threadIdx.x;
  int w   = tid >> 6;
  int q   = (tid >> 4) & 3;   // quad within wave
  int l15 = tid & 15;
  int itile  = blockIdx.x & (ITILES - 1);
  int jsplit = blockIdx.x >> 6;
  int i0 = itile * ROWS_PER_BLOCK + w * 64;

  // A fragments: 4 i-subtiles x 4 k-chunks, 16 B each. A[m=lane&15][k=quad*8+j].
  short8 afrag[4][4];
  const short* A = (const short*)z1n;
#pragma unroll
  for (int ii = 0; ii < 4; ++ii) {
    const short* rp = A + (size_t)(i0 + ii * 16 + l15) * DIM;
#pragma unroll
    for (int kk = 0; kk < 4; ++kk)
      afrag[ii][kk] = *(const short8*)(rp + q * 8 + kk * 32);
  }

  float rowsum[4][4];
#pragma unroll
  for (int ii = 0; ii < 4; ++ii)
#pragma unroll
    for (int r = 0; r < 4; ++r) rowsum[ii][r] = 0.0f;

  const char* Bbase = (const char*)z2n + (size_t)jsplit * COLS_PER_BLOCK * (DIM * 2);

  for (int c = 0; c < NCHUNK; ++c) {
    const char* chunk = Bbase + (size_t)c * JCHUNK * (DIM * 2);
    // stage 32 KB: 8 rounds x 256 thr x 16 B. LDS dest lane-linear (required);
    // swizzle applied on the *global* fetch granule.
#pragma unroll
    for (int r = 0; r < 8; ++r) {
      int G    = r * 256 + tid;       // LDS granule 0..2047
      int rowl = G >> 4;              // chunk-local B row
      int gl   = G & 15;              // granule within row
      int gsrc = gl ^ (rowl & 15);    // swizzled source granule
      gload_lds16(chunk + (size_t)rowl * 256 + gsrc * 16,
                  (char*)lds8 + (size_t)G * 16);
    }
    __syncthreads();

#pragma unroll
    for (int jj = 0; jj < 8; ++jj) {
      short8 bfr[4];
#pragma unroll
      for (int kk = 0; kk < 4; ++kk)
        bfr[kk] = lds8[(jj * 16 + l15) * 16 + ((q + 4 * kk) ^ l15)];
#pragma unroll
      for (int ii = 0; ii < 4; ++ii) {
        floatx4 acc = {0.f, 0.f, 0.f, 0.f};
#pragma unroll
        for (int kk = 0; kk < 4; ++kk)
          acc = __builtin_amdgcn_mfma_f32_16x16x32_bf16(afrag[ii][kk], bfr[kk], acc, 0, 0, 0);
        // C/D layout: col = lane&15, row = quad*4 + r. Accumulate exp into rowsum.
#pragma unroll
        for (int r = 0; r < 4; ++r)
          rowsum[ii][r] += __expf(2.0f * acc[r]);
      }
    }
    __syncthreads();
  }

  // reduce the 16 columns-per-tile partials (spread over l15) and commit
#pragma unroll
  for (int ii = 0; ii < 4; ++ii)
#pragma unroll
    for (int r = 0; r < 4; ++r) {
      float v = rowsum[ii][r];
      v += __shfl_xor(v, 1);
      v += __shfl_xor(v, 2);
      v += __shfl_xor(v, 4);
      v += __shfl_xor(v, 8);
      if (l15 == 0) atomicAdd(&denom[i0 + ii * 16 + q * 4 + r], v);
    }
}

// ---------------- Kernel 3: loss = -mean(2*diag - log(denom+eps)) -----------
__global__ __launch_bounds__(256) void loss_kernel(
    const float* __restrict__ denom, const float* __restrict__ diag,
    float* __restrict__ out) {
  int tid = threadIdx.x;
  float acc = 0.f;
  for (int i = tid; i < N_ROWS; i += 256)
    acc += 2.0f * diag[i] - logf(denom[i] + 1e-8f);
#pragma unroll
  for (int m = 32; m >= 1; m >>= 1) acc += __shfl_xor(acc, m);
  __shared__ float wsum[4];
  if ((tid & 63) == 0) wsum[tid >> 6] = acc;
  __syncthreads();
  if (tid == 0)
    out[0] = -(wsum[0] + wsum[1] + wsum[2] + wsum[3]) * (1.0f / N_ROWS);
}

extern "C" void kernel_launch(void* const* d_in, const int* in_sizes, int n_in,
                              void* d_out, int out_size, void* d_ws, size_t ws_size,
                              hipStream_t stream) {
  const float* z1 = (const float*)d_in[0];
  const float* z2 = (const float*)d_in[1];
  char* ws = (char*)d_ws;
  __hip_bfloat16* z1n = (__hip_bfloat16*)ws;                                   // 4 MB
  __hip_bfloat16* z2n = (__hip_bfloat16*)(ws + (size_t)N_ROWS * DIM * 2);      // 4 MB
  float* denom = (float*)(ws + (size_t)N_ROWS * DIM * 4);                      // 64 KB
  float* diag  = (float*)(ws + (size_t)N_ROWS * DIM * 4 + (size_t)N_ROWS * 4); // 64 KB

  norm_kernel<<<N_ROWS / 4, 256, 0, stream>>>(z1, z2, z1n, z2n, diag, denom);
  sim_kernel<<<ITILES * JSPLIT, 256, 0, stream>>>(z1n, z2n, denom);
  loss_kernel<<<1, 256, 0, stream>>>(denom, diag, (float*)d_out);
}

// Round 2
// 138.444 us; speedup vs baseline: 1.1796x; 1.1796x over previous
//
#include <hip/hip_runtime.h>
#include <hip/hip_bf16.h>

// CrossViewContrast: loss = -mean_i( 2*<z1n_i,z2n_i> - log(sum_j exp(2*<z1n_i,z2n_j>) + 1e-8) )
// N=16384, D=128. bf16 MFMA GEMM with exp2 rowsum epilogue; sim never materialized.
// R2: JSPLIT 16 (4 blocks/CU), scale 2*log2e baked into z1n bf16 (epilogue = exp2+add only).

#define N_ROWS 16384
#define DIM 128
#define JSPLIT 16
#define COLS_PER_BLOCK (N_ROWS / JSPLIT)   // 1024
#define JCHUNK 128
#define NCHUNK (COLS_PER_BLOCK / JCHUNK)   // 8
#define ROWS_PER_BLOCK 256
#define ITILES (N_ROWS / ROWS_PER_BLOCK)   // 64

// exp(2*sim) = 2^(SCALE*sim); SCALE baked into z1n so MFMA acc is already in log2 domain.
#define SCALE 2.8853900817779268f  // 2 * log2(e)

typedef __attribute__((ext_vector_type(8))) short short8;   // 8 bf16 = 4 VGPRs (MFMA A/B frag)
typedef __attribute__((ext_vector_type(4))) float floatx4;  // MFMA C/D frag

#if __has_builtin(__builtin_amdgcn_exp2f)
#define EXP2(x) __builtin_amdgcn_exp2f(x)
#else
#define EXP2(x) exp2f(x)
#endif

__device__ inline void gload_lds16(const void* gptr, void* lptr) {
  __builtin_amdgcn_global_load_lds(
      (const __attribute__((address_space(1))) void*)gptr,
      (__attribute__((address_space(3))) void*)lptr, 16, 0, 0);
}

// ---------------- Kernel 1: row norms + diagonal + bf16 cast + denom zero ----
__global__ __launch_bounds__(256) void norm_kernel(
    const float* __restrict__ z1, const float* __restrict__ z2,
    __hip_bfloat16* __restrict__ z1n, __hip_bfloat16* __restrict__ z2n,
    float* __restrict__ diag, float* __restrict__ denom) {
  int tid = threadIdx.x;
  int wave = tid >> 6, lane = tid & 63;
  int row = blockIdx.x * 4 + wave;   // one wave per row
  const float2* p1 = (const float2*)(z1 + (size_t)row * DIM);
  const float2* p2 = (const float2*)(z2 + (size_t)row * DIM);
  float2 a = p1[lane], b = p2[lane];
  float s11 = a.x * a.x + a.y * a.y;
  float s22 = b.x * b.x + b.y * b.y;
  float s12 = a.x * b.x + a.y * b.y;
#pragma unroll
  for (int m = 32; m >= 1; m >>= 1) {
    s11 += __shfl_xor(s11, m);
    s22 += __shfl_xor(s22, m);
    s12 += __shfl_xor(s12, m);
  }
  float inv1 = 1.0f / fmaxf(sqrtf(s11), 1e-12f);  // torch F.normalize eps
  float inv2 = 1.0f / fmaxf(sqrtf(s22), 1e-12f);
  float sc1 = inv1 * SCALE;                        // bake exp scale into A
  __hip_bfloat162 o1, o2;
  o1.x = __float2bfloat16(a.x * sc1);  o1.y = __float2bfloat16(a.y * sc1);
  o2.x = __float2bfloat16(b.x * inv2); o2.y = __float2bfloat16(b.y * inv2);
  ((__hip_bfloat162*)(z1n + (size_t)row * DIM))[lane] = o1;
  ((__hip_bfloat162*)(z2n + (size_t)row * DIM))[lane] = o2;
  if (lane == 0) diag[row] = s12 * inv1 * inv2;          // exact fp32 diagonal
  if (wave == 0 && lane < 4) denom[blockIdx.x * 4 + lane] = 0.0f;
}

// ---------------- Kernel 2: denom_i += sum_j exp(2*sim_ij), bf16 MFMA -------
// Block: 4 waves; wave w owns rows [i0+w*64, +64) (A frags in registers).
// B chunk: 128 cols x 128 K bf16 = 32 KB staged in LDS via global_load_lds,
// 16B-granule XOR swizzle (phys = logical ^ (row&15)) -> 0 bank conflicts (R1-verified).
__global__ __launch_bounds__(256, 4) void sim_kernel(
    const __hip_bfloat16* __restrict__ z1n,
    const __hip_bfloat16* __restrict__ z2n,
    float* __restrict__ denom) {
  __shared__ short8 lds8[JCHUNK * 16];  // 2048 granules * 16 B = 32 KB

  int tid = threadIdx.x;
  int w   = tid >> 6;
  int q   = (tid >> 4) & 3;   // quad within wave
  int l15 = tid & 15;
  int itile  = blockIdx.x & (ITILES - 1);
  int jsplit = blockIdx.x >> 6;
  int i0 = itile * ROWS_PER_BLOCK + w * 64;

  // A fragments: 4 i-subtiles x 4 k-chunks, 16 B each. A[m=lane&15][k=quad*8+j].
  short8 afrag[4][4];
  const short* A = (const short*)z1n;
#pragma unroll
  for (int ii = 0; ii < 4; ++ii) {
    const short* rp = A + (size_t)(i0 + ii * 16 + l15) * DIM;
#pragma unroll
    for (int kk = 0; kk < 4; ++kk)
      afrag[ii][kk] = *(const short8*)(rp + q * 8 + kk * 32);
  }

  floatx4 rowsum[4];
#pragma unroll
  for (int ii = 0; ii < 4; ++ii) rowsum[ii] = (floatx4){0.f, 0.f, 0.f, 0.f};

  const char* Bbase = (const char*)z2n + (size_t)jsplit * COLS_PER_BLOCK * (DIM * 2);

  for (int c = 0; c < NCHUNK; ++c) {
    const char* chunk = Bbase + (size_t)c * JCHUNK * (DIM * 2);
    // stage 32 KB: 8 rounds x 256 thr x 16 B. LDS dest lane-linear (required);
    // swizzle applied on the *global* fetch granule.
#pragma unroll
    for (int r = 0; r < 8; ++r) {
      int G    = r * 256 + tid;       // LDS granule 0..2047
      int rowl = G >> 4;              // chunk-local B row
      int gl   = G & 15;              // granule within row
      int gsrc = gl ^ (rowl & 15);    // swizzled source granule
      gload_lds16(chunk + (size_t)rowl * 256 + gsrc * 16,
                  (char*)lds8 + (size_t)G * 16);
    }
    __syncthreads();

#pragma unroll
    for (int jj = 0; jj < 8; ++jj) {
      short8 bfr[4];
#pragma unroll
      for (int kk = 0; kk < 4; ++kk)
        bfr[kk] = lds8[(jj * 16 + l15) * 16 + ((q + 4 * kk) ^ l15)];
#pragma unroll
      for (int ii = 0; ii < 4; ++ii) {
        floatx4 acc = {0.f, 0.f, 0.f, 0.f};
#pragma unroll
        for (int kk = 0; kk < 4; ++kk)
          acc = __builtin_amdgcn_mfma_f32_16x16x32_bf16(afrag[ii][kk], bfr[kk], acc, 0, 0, 0);
        // acc is already SCALE*sim (log2 domain). C/D: col=lane&15, row=quad*4+r.
        floatx4 e;
#pragma unroll
        for (int r = 0; r < 4; ++r) e[r] = EXP2(acc[r]);
        rowsum[ii] += e;   // packed f32 adds
      }
    }
    __syncthreads();
  }

  // reduce the 16 columns-per-tile partials (spread over l15) and commit
#pragma unroll
  for (int ii = 0; ii < 4; ++ii)
#pragma unroll
    for (int r = 0; r < 4; ++r) {
      float v = rowsum[ii][r];
      v += __shfl_xor(v, 1);
      v += __shfl_xor(v, 2);
      v += __shfl_xor(v, 4);
      v += __shfl_xor(v, 8);
      if (l15 == 0) atomicAdd(&denom[i0 + ii * 16 + q * 4 + r], v);
    }
}

// ---------------- Kernel 3: loss = -mean(2*diag - log(denom+eps)) -----------
__global__ __launch_bounds__(1024) void loss_kernel(
    const float* __restrict__ denom, const float* __restrict__ diag,
    float* __restrict__ out) {
  int tid = threadIdx.x;
  float acc = 0.f;
  for (int i = tid; i < N_ROWS; i += 1024)
    acc += 2.0f * diag[i] - logf(denom[i] + 1e-8f);
#pragma unroll
  for (int m = 32; m >= 1; m >>= 1) acc += __shfl_xor(acc, m);
  __shared__ float wsum[16];
  if ((tid & 63) == 0) wsum[tid >> 6] = acc;
  __syncthreads();
  if (tid == 0) {
    float s = 0.f;
#pragma unroll
    for (int k = 0; k < 16; ++k) s += wsum[k];
    out[0] = -s * (1.0f / N_ROWS);
  }
}

extern "C" void kernel_launch(void* const* d_in, const int* in_sizes, int n_in,
                              void* d_out, int out_size, void* d_ws, size_t ws_size,
                              hipStream_t stream) {
  const float* z1 = (const float*)d_in[0];
  const float* z2 = (const float*)d_in[1];
  char* ws = (char*)d_ws;
  __hip_bfloat16* z1n = (__hip_bfloat16*)ws;                                   // 4 MB
  __hip_bfloat16* z2n = (__hip_bfloat16*)(ws + (size_t)N_ROWS * DIM * 2);      // 4 MB
  float* denom = (float*)(ws + (size_t)N_ROWS * DIM * 4);                      // 64 KB
  float* diag  = (float*)(ws + (size_t)N_ROWS * DIM * 4 + (size_t)N_ROWS * 4); // 64 KB

  norm_kernel<<<N_ROWS / 4, 256, 0, stream>>>(z1, z2, z1n, z2n, diag, denom);
  sim_kernel<<<ITILES * JSPLIT, 256, 0, stream>>>(z1n, z2n, denom);
  loss_kernel<<<1, 1024, 0, stream>>>(denom, diag, (float*)d_out);
}

// Round 3
// 134.189 us; speedup vs baseline: 1.2170x; 1.0317x over previous
//
#include <hip/hip_runtime.h>
#include <hip/hip_bf16.h>

// CrossViewContrast: loss = -mean_i( 2*<z1n_i,z2n_i> - log(sum_j exp(2*<z1n_i,z2n_j>) + 1e-8) )
// N=16384, D=128. bf16 MFMA GEMM with exp2 rowsum epilogue; sim never materialized.
// R2: JSPLIT 16 (4 blocks/CU), 2*log2e baked into z1n (epilogue = exp2+add). sim 96->76us.
// R3: double-buffered 16KB chunks, prefetch c+1 before compute of c, one barrier/chunk
//     -> hide the global_load_lds vmcnt drain that stalled the 2-barrier structure.

#define N_ROWS 16384
#define DIM 128
#define JSPLIT 16
#define COLS_PER_BLOCK (N_ROWS / JSPLIT)   // 1024
#define JCHUNK 64
#define NCHUNK (COLS_PER_BLOCK / JCHUNK)   // 16
#define GRANULES (JCHUNK * 16)             // 1024 16B-granules per buffer (16 KB)
#define ROWS_PER_BLOCK 256
#define ITILES (N_ROWS / ROWS_PER_BLOCK)   // 64

// exp(2*sim) = 2^(SCALE*sim); SCALE baked into z1n so MFMA acc is already in log2 domain.
#define SCALE 2.8853900817779268f  // 2 * log2(e)

typedef __attribute__((ext_vector_type(8))) short short8;   // 8 bf16 = 4 VGPRs (MFMA A/B frag)
typedef __attribute__((ext_vector_type(4))) float floatx4;  // MFMA C/D frag

#if __has_builtin(__builtin_amdgcn_exp2f)
#define EXP2(x) __builtin_amdgcn_exp2f(x)
#else
#define EXP2(x) exp2f(x)
#endif

__device__ inline void gload_lds16(const void* gptr, void* lptr) {
  __builtin_amdgcn_global_load_lds(
      (const __attribute__((address_space(1))) void*)gptr,
      (__attribute__((address_space(3))) void*)lptr, 16, 0, 0);
}

// ---------------- Kernel 1: row norms + diagonal + bf16 cast + denom zero ----
__global__ __launch_bounds__(256) void norm_kernel(
    const float* __restrict__ z1, const float* __restrict__ z2,
    __hip_bfloat16* __restrict__ z1n, __hip_bfloat16* __restrict__ z2n,
    float* __restrict__ diag, float* __restrict__ denom) {
  int tid = threadIdx.x;
  int wave = tid >> 6, lane = tid & 63;
  int row = blockIdx.x * 4 + wave;   // one wave per row
  const float2* p1 = (const float2*)(z1 + (size_t)row * DIM);
  const float2* p2 = (const float2*)(z2 + (size_t)row * DIM);
  float2 a = p1[lane], b = p2[lane];
  float s11 = a.x * a.x + a.y * a.y;
  float s22 = b.x * b.x + b.y * b.y;
  float s12 = a.x * b.x + a.y * b.y;
#pragma unroll
  for (int m = 32; m >= 1; m >>= 1) {
    s11 += __shfl_xor(s11, m);
    s22 += __shfl_xor(s22, m);
    s12 += __shfl_xor(s12, m);
  }
  float inv1 = 1.0f / fmaxf(sqrtf(s11), 1e-12f);  // torch F.normalize eps
  float inv2 = 1.0f / fmaxf(sqrtf(s22), 1e-12f);
  float sc1 = inv1 * SCALE;                        // bake exp scale into A
  __hip_bfloat162 o1, o2;
  o1.x = __float2bfloat16(a.x * sc1);  o1.y = __float2bfloat16(a.y * sc1);
  o2.x = __float2bfloat16(b.x * inv2); o2.y = __float2bfloat16(b.y * inv2);
  ((__hip_bfloat162*)(z1n + (size_t)row * DIM))[lane] = o1;
  ((__hip_bfloat162*)(z2n + (size_t)row * DIM))[lane] = o2;
  if (lane == 0) diag[row] = s12 * inv1 * inv2;          // exact fp32 diagonal
  if (wave == 0 && lane < 4) denom[blockIdx.x * 4 + lane] = 0.0f;
}

// ---------------- Kernel 2: denom_i += sum_j exp(2*sim_ij), bf16 MFMA -------
// Block: 4 waves; wave w owns rows [i0+w*64, +64) (A frags in registers/AGPRs).
// B chunk: 64 cols x 128 K bf16 = 16 KB in LDS, double-buffered (32 KB total).
// 16B-granule XOR swizzle (phys = logical ^ (row&15)) -> 0 bank conflicts (R1-verified).
// Prefetch chunk c+1 via global_load_lds BEFORE computing chunk c; single barrier
// per chunk so the vmcnt drain overlaps a full chunk of MFMA+exp compute.
__global__ __launch_bounds__(256, 4) void sim_kernel(
    const __hip_bfloat16* __restrict__ z1n,
    const __hip_bfloat16* __restrict__ z2n,
    float* __restrict__ denom) {
  __shared__ short8 lds8[2][GRANULES];  // 2 x 16 KB

  int tid = threadIdx.x;
  int w   = tid >> 6;
  int q   = (tid >> 4) & 3;   // quad within wave
  int l15 = tid & 15;
  int itile  = blockIdx.x & (ITILES - 1);
  int jsplit = blockIdx.x >> 6;
  int i0 = itile * ROWS_PER_BLOCK + w * 64;

  // A fragments: 4 i-subtiles x 4 k-chunks, 16 B each. A[m=lane&15][k=quad*8+j].
  short8 afrag[4][4];
  const short* A = (const short*)z1n;
#pragma unroll
  for (int ii = 0; ii < 4; ++ii) {
    const short* rp = A + (size_t)(i0 + ii * 16 + l15) * DIM;
#pragma unroll
    for (int kk = 0; kk < 4; ++kk)
      afrag[ii][kk] = *(const short8*)(rp + q * 8 + kk * 32);
  }

  floatx4 rowsum[4];
#pragma unroll
  for (int ii = 0; ii < 4; ++ii) rowsum[ii] = (floatx4){0.f, 0.f, 0.f, 0.f};

  const char* Bbase = (const char*)z2n + (size_t)jsplit * COLS_PER_BLOCK * (DIM * 2);

  // stage one 16 KB chunk: 4 rounds x 256 thr x 16 B, XOR-swizzled global granule.
  // LDS dest must stay lane-linear (global_load_lds constraint).
#define STAGE(cidx, buf)                                                     \
  do {                                                                       \
    const char* _ck = Bbase + (size_t)(cidx) * JCHUNK * 256;                 \
    char* _dst = (char*)&lds8[buf][0];                                       \
    _Pragma("unroll")                                                        \
    for (int _r = 0; _r < 4; ++_r) {                                         \
      int _G = _r * 256 + tid;                                               \
      int _rowl = _G >> 4, _gl = _G & 15;                                    \
      int _gsrc = _gl ^ (_rowl & 15);                                        \
      gload_lds16(_ck + (size_t)_rowl * 256 + _gsrc * 16,                    \
                  _dst + (size_t)_G * 16);                                   \
    }                                                                        \
  } while (0)

  STAGE(0, 0);
  __syncthreads();

  for (int c = 0; c < NCHUNK; ++c) {
    if (c + 1 < NCHUNK) STAGE(c + 1, (c + 1) & 1);  // prefetch next chunk
    const short8* buf = &lds8[c & 1][0];

#pragma unroll
    for (int jj = 0; jj < 4; ++jj) {
      short8 bfr[4];
#pragma unroll
      for (int kk = 0; kk < 4; ++kk)
        bfr[kk] = buf[(jj * 16 + l15) * 16 + ((q + 4 * kk) ^ l15)];
#pragma unroll
      for (int ii = 0; ii < 4; ++ii) {
        floatx4 acc = {0.f, 0.f, 0.f, 0.f};
#pragma unroll
        for (int kk = 0; kk < 4; ++kk)
          acc = __builtin_amdgcn_mfma_f32_16x16x32_bf16(afrag[ii][kk], bfr[kk], acc, 0, 0, 0);
        // acc is already SCALE*sim (log2 domain). C/D: col=lane&15, row=quad*4+r.
        floatx4 e;
#pragma unroll
        for (int r = 0; r < 4; ++r) e[r] = EXP2(acc[r]);
        rowsum[ii] += e;   // packed f32 adds
      }
    }
    __syncthreads();  // drains prefetch (already landed) + guards buf reuse
  }

  // reduce the 16 columns-per-tile partials (spread over l15) and commit
#pragma unroll
  for (int ii = 0; ii < 4; ++ii)
#pragma unroll
    for (int r = 0; r < 4; ++r) {
      float v = rowsum[ii][r];
      v += __shfl_xor(v, 1);
      v += __shfl_xor(v, 2);
      v += __shfl_xor(v, 4);
      v += __shfl_xor(v, 8);
      if (l15 == 0) atomicAdd(&denom[i0 + ii * 16 + q * 4 + r], v);
    }
}

// ---------------- Kernel 3: loss = -mean(2*diag - log(denom+eps)) -----------
__global__ __launch_bounds__(1024) void loss_kernel(
    const float* __restrict__ denom, const float* __restrict__ diag,
    float* __restrict__ out) {
  int tid = threadIdx.x;
  const float4* d4 = (const float4*)denom;
  const float4* g4 = (const float4*)diag;
  float acc = 0.f;
#pragma unroll
  for (int k = 0; k < 4; ++k) {
    float4 dv = d4[tid + k * 1024];
    float4 gv = g4[tid + k * 1024];
    acc += 2.0f * gv.x - logf(dv.x + 1e-8f);
    acc += 2.0f * gv.y - logf(dv.y + 1e-8f);
    acc += 2.0f * gv.z - logf(dv.z + 1e-8f);
    acc += 2.0f * gv.w - logf(dv.w + 1e-8f);
  }
#pragma unroll
  for (int m = 32; m >= 1; m >>= 1) acc += __shfl_xor(acc, m);
  __shared__ float wsum[16];
  if ((tid & 63) == 0) wsum[tid >> 6] = acc;
  __syncthreads();
  if (tid == 0) {
    float s = 0.f;
#pragma unroll
    for (int k = 0; k < 16; ++k) s += wsum[k];
    out[0] = -s * (1.0f / N_ROWS);
  }
}

extern "C" void kernel_launch(void* const* d_in, const int* in_sizes, int n_in,
                              void* d_out, int out_size, void* d_ws, size_t ws_size,
                              hipStream_t stream) {
  const float* z1 = (const float*)d_in[0];
  const float* z2 = (const float*)d_in[1];
  char* ws = (char*)d_ws;
  __hip_bfloat16* z1n = (__hip_bfloat16*)ws;                                   // 4 MB
  __hip_bfloat16* z2n = (__hip_bfloat16*)(ws + (size_t)N_ROWS * DIM * 2);      // 4 MB
  float* denom = (float*)(ws + (size_t)N_ROWS * DIM * 4);                      // 64 KB
  float* diag  = (float*)(ws + (size_t)N_ROWS * DIM * 4 + (size_t)N_ROWS * 4); // 64 KB

  norm_kernel<<<N_ROWS / 4, 256, 0, stream>>>(z1, z2, z1n, z2n, diag, denom);
  sim_kernel<<<ITILES * JSPLIT, 256, 0, stream>>>(z1n, z2n, denom);
  loss_kernel<<<1, 1024, 0, stream>>>(denom, diag, (float*)d_out);
}

// Round 4
// 132.381 us; speedup vs baseline: 1.2337x; 1.0137x over previous
//
#include <hip/hip_runtime.h>
#include <hip/hip_bf16.h>

// CrossViewContrast: loss = -mean_i( 2*<z1n_i,z2n_i> - log(sum_j exp(2*<z1n_i,z2n_j>) + 1e-8) )
// N=16384, D=128. bf16 MFMA GEMM with exp2 rowsum epilogue; sim never materialized.
// R2: JSPLIT 16, 2*log2e baked into z1n (epilogue = exp2+add). sim 96->76us.
// R3: dbuf prefetch: neutral (73.5us) -> stall is NOT vmcnt drain; it's no MFMA/VALU
//     overlap at 4 waves/SIMD (128 unified regs/wave + 32KB LDS cap occupancy).
// R4: occupancy push: 32 rows/wave (afrag 32 regs -> ~80 unified), 16KB LDS/block
//     (JCHUNK=32 dbuf), grid 2048 -> target 6 waves/SIMD so MFMA & VALU pipes overlap.

#define N_ROWS 16384
#define DIM 128
#define JSPLIT 16
#define COLS_PER_BLOCK (N_ROWS / JSPLIT)   // 1024
#define JCHUNK 32
#define NCHUNK (COLS_PER_BLOCK / JCHUNK)   // 32
#define GRANULES (JCHUNK * 16)             // 512 16B-granules per buffer (8 KB)
#define ROWS_PER_BLOCK 128
#define ITILES (N_ROWS / ROWS_PER_BLOCK)   // 128

// exp(2*sim) = 2^(SCALE*sim); SCALE baked into z1n so MFMA acc is already in log2 domain.
#define SCALE 2.8853900817779268f  // 2 * log2(e)

typedef __attribute__((ext_vector_type(8))) short short8;   // 8 bf16 = 4 VGPRs (MFMA A/B frag)
typedef __attribute__((ext_vector_type(4))) float floatx4;  // MFMA C/D frag

#if __has_builtin(__builtin_amdgcn_exp2f)
#define EXP2(x) __builtin_amdgcn_exp2f(x)
#else
#define EXP2(x) exp2f(x)
#endif

__device__ inline void gload_lds16(const void* gptr, void* lptr) {
  __builtin_amdgcn_global_load_lds(
      (const __attribute__((address_space(1))) void*)gptr,
      (__attribute__((address_space(3))) void*)lptr, 16, 0, 0);
}

// ---------------- Kernel 1: row norms + diagonal + bf16 cast + denom zero ----
__global__ __launch_bounds__(256) void norm_kernel(
    const float* __restrict__ z1, const float* __restrict__ z2,
    __hip_bfloat16* __restrict__ z1n, __hip_bfloat16* __restrict__ z2n,
    float* __restrict__ diag, float* __restrict__ denom) {
  int tid = threadIdx.x;
  int wave = tid >> 6, lane = tid & 63;
  int row = blockIdx.x * 4 + wave;   // one wave per row
  const float2* p1 = (const float2*)(z1 + (size_t)row * DIM);
  const float2* p2 = (const float2*)(z2 + (size_t)row * DIM);
  float2 a = p1[lane], b = p2[lane];
  float s11 = a.x * a.x + a.y * a.y;
  float s22 = b.x * b.x + b.y * b.y;
  float s12 = a.x * b.x + a.y * b.y;
#pragma unroll
  for (int m = 32; m >= 1; m >>= 1) {
    s11 += __shfl_xor(s11, m);
    s22 += __shfl_xor(s22, m);
    s12 += __shfl_xor(s12, m);
  }
  float inv1 = 1.0f / fmaxf(sqrtf(s11), 1e-12f);  // torch F.normalize eps
  float inv2 = 1.0f / fmaxf(sqrtf(s22), 1e-12f);
  float sc1 = inv1 * SCALE;                        // bake exp scale into A
  __hip_bfloat162 o1, o2;
  o1.x = __float2bfloat16(a.x * sc1);  o1.y = __float2bfloat16(a.y * sc1);
  o2.x = __float2bfloat16(b.x * inv2); o2.y = __float2bfloat16(b.y * inv2);
  ((__hip_bfloat162*)(z1n + (size_t)row * DIM))[lane] = o1;
  ((__hip_bfloat162*)(z2n + (size_t)row * DIM))[lane] = o2;
  if (lane == 0) diag[row] = s12 * inv1 * inv2;          // exact fp32 diagonal
  if (wave == 0 && lane < 4) denom[blockIdx.x * 4 + lane] = 0.0f;
}

// ---------------- Kernel 2: denom_i += sum_j exp(2*sim_ij), bf16 MFMA -------
// Block: 4 waves; wave w owns rows [i0+w*32, +32) (afrag 32 regs -> ~80 unified
// regs/wave -> 6 waves/SIMD). B chunk: 32 cols x 128 K = 8 KB, double-buffered
// (16 KB LDS/block -> 6+ blocks/CU). XOR-swizzled granules: 0 bank conflicts.
__global__ __launch_bounds__(256, 6) void sim_kernel(
    const __hip_bfloat16* __restrict__ z1n,
    const __hip_bfloat16* __restrict__ z2n,
    float* __restrict__ denom) {
  __shared__ short8 lds8[2][GRANULES];  // 2 x 8 KB

  int tid = threadIdx.x;
  int w   = tid >> 6;
  int q   = (tid >> 4) & 3;   // quad within wave
  int l15 = tid & 15;
  int itile  = blockIdx.x & (ITILES - 1);
  int jsplit = blockIdx.x >> 7;
  int i0 = itile * ROWS_PER_BLOCK + w * 32;

  // A fragments: 2 i-subtiles x 4 k-chunks, 16 B each. A[m=lane&15][k=quad*8+j].
  short8 afrag[2][4];
  const short* A = (const short*)z1n;
#pragma unroll
  for (int ii = 0; ii < 2; ++ii) {
    const short* rp = A + (size_t)(i0 + ii * 16 + l15) * DIM;
#pragma unroll
    for (int kk = 0; kk < 4; ++kk)
      afrag[ii][kk] = *(const short8*)(rp + q * 8 + kk * 32);
  }

  floatx4 rowsum[2];
#pragma unroll
  for (int ii = 0; ii < 2; ++ii) rowsum[ii] = (floatx4){0.f, 0.f, 0.f, 0.f};

  const char* Bbase = (const char*)z2n + (size_t)jsplit * COLS_PER_BLOCK * (DIM * 2);

  // stage one 8 KB chunk: 2 rounds x 256 thr x 16 B, XOR-swizzled global granule.
  // LDS dest must stay lane-linear (global_load_lds constraint).
#define STAGE(cidx, buf)                                                     \
  do {                                                                       \
    const char* _ck = Bbase + (size_t)(cidx) * JCHUNK * 256;                 \
    char* _dst = (char*)&lds8[buf][0];                                       \
    _Pragma("unroll")                                                        \
    for (int _r = 0; _r < 2; ++_r) {                                         \
      int _G = _r * 256 + tid;                                               \
      int _rowl = _G >> 4, _gl = _G & 15;                                    \
      int _gsrc = _gl ^ (_rowl & 15);                                        \
      gload_lds16(_ck + (size_t)_rowl * 256 + _gsrc * 16,                    \
                  _dst + (size_t)_G * 16);                                   \
    }                                                                        \
  } while (0)

  STAGE(0, 0);
  __syncthreads();

  for (int c = 0; c < NCHUNK; ++c) {
    if (c + 1 < NCHUNK) STAGE(c + 1, (c + 1) & 1);  // prefetch next chunk
    const short8* buf = &lds8[c & 1][0];

#pragma unroll
    for (int jj = 0; jj < 2; ++jj) {
      short8 bfr[4];
#pragma unroll
      for (int kk = 0; kk < 4; ++kk)
        bfr[kk] = buf[(jj * 16 + l15) * 16 + ((q + 4 * kk) ^ l15)];
#pragma unroll
      for (int ii = 0; ii < 2; ++ii) {
        floatx4 acc = {0.f, 0.f, 0.f, 0.f};
#pragma unroll
        for (int kk = 0; kk < 4; ++kk)
          acc = __builtin_amdgcn_mfma_f32_16x16x32_bf16(afrag[ii][kk], bfr[kk], acc, 0, 0, 0);
        // acc is already SCALE*sim (log2 domain). C/D: col=lane&15, row=quad*4+r.
        floatx4 e;
#pragma unroll
        for (int r = 0; r < 4; ++r) e[r] = EXP2(acc[r]);
        rowsum[ii] += e;   // packed f32 adds
      }
    }
    __syncthreads();  // guards buf reuse
  }

  // reduce the 16 columns-per-tile partials (spread over l15) and commit
#pragma unroll
  for (int ii = 0; ii < 2; ++ii)
#pragma unroll
    for (int r = 0; r < 4; ++r) {
      float v = rowsum[ii][r];
      v += __shfl_xor(v, 1);
      v += __shfl_xor(v, 2);
      v += __shfl_xor(v, 4);
      v += __shfl_xor(v, 8);
      if (l15 == 0) atomicAdd(&denom[i0 + ii * 16 + q * 4 + r], v);
    }
}

// ---------------- Kernel 3: loss = -mean(2*diag - log(denom+eps)) -----------
__global__ __launch_bounds__(1024) void loss_kernel(
    const float* __restrict__ denom, const float* __restrict__ diag,
    float* __restrict__ out) {
  int tid = threadIdx.x;
  const float4* d4 = (const float4*)denom;
  const float4* g4 = (const float4*)diag;
  float acc = 0.f;
#pragma unroll
  for (int k = 0; k < 4; ++k) {
    float4 dv = d4[tid + k * 1024];
    float4 gv = g4[tid + k * 1024];
    acc += 2.0f * gv.x - __logf(dv.x + 1e-8f);
    acc += 2.0f * gv.y - __logf(dv.y + 1e-8f);
    acc += 2.0f * gv.z - __logf(dv.z + 1e-8f);
    acc += 2.0f * gv.w - __logf(dv.w + 1e-8f);
  }
#pragma unroll
  for (int m = 32; m >= 1; m >>= 1) acc += __shfl_xor(acc, m);
  __shared__ float wsum[16];
  if ((tid & 63) == 0) wsum[tid >> 6] = acc;
  __syncthreads();
  if (tid == 0) {
    float s = 0.f;
#pragma unroll
    for (int k = 0; k < 16; ++k) s += wsum[k];
    out[0] = -s * (1.0f / N_ROWS);
  }
}

extern "C" void kernel_launch(void* const* d_in, const int* in_sizes, int n_in,
                              void* d_out, int out_size, void* d_ws, size_t ws_size,
                              hipStream_t stream) {
  const float* z1 = (const float*)d_in[0];
  const float* z2 = (const float*)d_in[1];
  char* ws = (char*)d_ws;
  __hip_bfloat16* z1n = (__hip_bfloat16*)ws;                                   // 4 MB
  __hip_bfloat16* z2n = (__hip_bfloat16*)(ws + (size_t)N_ROWS * DIM * 2);      // 4 MB
  float* denom = (float*)(ws + (size_t)N_ROWS * DIM * 4);                      // 64 KB
  float* diag  = (float*)(ws + (size_t)N_ROWS * DIM * 4 + (size_t)N_ROWS * 4); // 64 KB

  norm_kernel<<<N_ROWS / 4, 256, 0, stream>>>(z1, z2, z1n, z2n, diag, denom);
  sim_kernel<<<ITILES * JSPLIT, 256, 0, stream>>>(z1n, z2n, denom);
  loss_kernel<<<1, 1024, 0, stream>>>(denom, diag, (float*)d_out);
}